// Round 2
// baseline (504.968 us; speedup 1.0000x reference)
//
#include <hip/hip_runtime.h>
#include <hip/hip_fp16.h>

#define H 256
#define W 256
#define BS 8
#define IC 16          // in_ch (flow fields per batch; also out channels)
#define OCH 32         // conv output channels = 2*IC
#define NSTEPS 7
#define PLANE (H*W)            // 65536
#define NFIELDS (BS*IC)        // 128
#define BN_N (BS*PLANE)        // 524288
#define BN_EPS 1e-5f
// padded plane: interior (y,x) at (y+1, x+1), pitch 260, rows 0..258 used
#define PW 260
#define PSZ (260 * 260)

// ---------------------------------------------------------------------------
// K0: vec_w [oc][ic][3][3] -> wTh [(ic*9+k)][p] as half2 pairs (oc 2p, 2p+1)
// ---------------------------------------------------------------------------
__global__ void transpose_w_kernel(const float* __restrict__ w,
                                   __half2* __restrict__ wTh) {
    for (int idx = threadIdx.x; idx < IC * 9 * 16; idx += blockDim.x) {
        int rc = idx >> 4;        // ic*9+k
        int p  = idx & 15;
        float lo = w[(2 * p) * (IC * 9) + rc];
        float hi = w[(2 * p + 1) * (IC * 9) + rc];
        wTh[idx] = __floats2half2_rn(lo, hi);
    }
}

// ---------------------------------------------------------------------------
// K1: zero the guard borders of the two padded step buffers + padded f16.
// ---------------------------------------------------------------------------
__global__ void guard_zero_kernel(unsigned* __restrict__ bufA,
                                  unsigned* __restrict__ bufB,
                                  unsigned short* __restrict__ f16p) {
    int p = blockIdx.x;           // 128 planes
    size_t pb = (size_t)p * PSZ;
    for (int i = threadIdx.x; i < 2064; i += blockDim.x) {
        int row, col;
        if (i < 1040) {
            int r = i / 260;
            row = (r == 0) ? 0 : 256 + r;     // 0,257,258,259
            col = i - r * 260;
        } else {
            int j = i - 1040;
            int c = j / 256;
            col = (c == 0) ? 0 : 256 + c;     // 0,257,258,259
            row = 1 + (j - c * 256);
        }
        size_t off = pb + (size_t)row * PW + col;
        bufA[off] = 0u;
        bufB[off] = 0u;
        f16p[off] = 0;
    }
}

// ---------------------------------------------------------------------------
// K2: 3x3 conv (16->32) + bias in PACKED FP16. Weights staged in LDS
// (block-uniform, broadcast ds_read) instead of per-FMA global loads:
// removes 2304 VMEM loads/thread that starved the FMA pipe (R1 theory).
// ---------------------------------------------------------------------------
__global__ __launch_bounds__(256, 4) void conv_kernel(
    const float* __restrict__ f, const __half2* __restrict__ wTh,
    const float* __restrict__ vec_b, __half2* __restrict__ vec_out,
    __half* __restrict__ f16p) {
    __shared__ __half sf[8][18][34];                   // 9.8 KB
    __shared__ __align__(16) __half2 sw[IC * 9 * 16];  // 9.2 KB weights

    int blk = blockIdx.x;              // 1024
    int xcd = blk & 7;
    int i   = blk >> 3;
    int b   = i >> 4;
    int j   = i & 15;
    int ty0 = ((xcd << 1) | (j >> 3)) * 16;
    int tx0 = (j & 7) * 32;
    int tid = threadIdx.x;
    int tyl = tid >> 5, txl = tid & 31;
    int y0p = ty0 + tyl, y1p = ty0 + tyl + 8, x = tx0 + txl;

    // stage weights to LDS (covered by the first __syncthreads below)
    for (int idx = tid; idx < IC * 9 * 16; idx += 256)
        sw[idx] = wTh[idx];

    __half2 acc0[16], acc1[16];
#pragma unroll
    for (int p = 0; p < 16; ++p) {
        __half2 bp = __floats2half2_rn(vec_b[2 * p], vec_b[2 * p + 1]);
        acc0[p] = bp; acc1[p] = bp;
    }

    for (int half = 0; half < 2; ++half) {
        if (half) __syncthreads();
        for (int idx = tid; idx < 8 * 18 * 34; idx += 256) {
            int ic = idx / 612;
            int r2 = idx - ic * 612;
            int r  = r2 / 34;
            int cc = r2 - r * 34;
            int gy = ty0 - 1 + r, gx = tx0 - 1 + cc;
            float v = 0.f;
            if (gy >= 0 && gy < H && gx >= 0 && gx < W)
                v = f[((size_t)(b * IC + half * 8 + ic) * H + gy) * W + gx];
            sf[ic][r][cc] = __float2half(v);
        }
        __syncthreads();

#pragma unroll 2
        for (int ic = 0; ic < 8; ++ic) {
            size_t fb16 = (size_t)(b * IC + half * 8 + ic) * PSZ;
            f16p[fb16 + (size_t)(y0p + 1) * PW + x + 1] = sf[ic][tyl + 1][txl + 1];
            f16p[fb16 + (size_t)(y1p + 1) * PW + x + 1] = sf[ic][tyl + 9][txl + 1];
#pragma unroll
            for (int k = 0; k < 9; ++k) {
                int ky = k / 3, kx = k - ky * 3;
                __half2 fv0 = __half2half2(sf[ic][tyl + ky][txl + kx]);
                __half2 fv1 = __half2half2(sf[ic][tyl + 8 + ky][txl + kx]);
                const __half2* wrow = sw + ((half * 8 + ic) * 9 + k) * 16;
#pragma unroll
                for (int p = 0; p < 16; ++p) {
                    __half2 wv = wrow[p];
                    acc0[p] = __hfma2(fv0, wv, acc0[p]);
                    acc1[p] = __hfma2(fv1, wv, acc1[p]);
                }
            }
        }
    }

#pragma unroll
    for (int c = 0; c < IC; ++c) {
        size_t pb = (size_t)(b * IC + c) * PLANE;
        vec_out[pb + y0p * W + x] = acc0[c];
        vec_out[pb + y1p * W + x] = acc1[c];
    }
}

// ---------------------------------------------------------------------------
// K3: per-channel sum / sumsq over the half2 conv output (unpadded).
// ---------------------------------------------------------------------------
__global__ __launch_bounds__(256) void stats_kernel(
    const __half2* __restrict__ vec, float* __restrict__ stats) {
    int blk   = blockIdx.x;            // 2048
    int n     = blk >> 4;
    int chunk = blk & 15;
    const __half2* p = vec + (size_t)n * PLANE + chunk * 4096;
    int tid = threadIdx.x;

    float s0 = 0.f, s1 = 0.f, q0 = 0.f, q1 = 0.f;
#pragma unroll 4
    for (int i = tid; i < 4096; i += 256) {
        float2 v = __half22float2(p[i]);
        s0 += v.x; s1 += v.y;
        q0 = fmaf(v.x, v.x, q0);
        q1 = fmaf(v.y, v.y, q1);
    }
#pragma unroll
    for (int off = 32; off > 0; off >>= 1) {
        s0 += __shfl_down(s0, off, 64);
        s1 += __shfl_down(s1, off, 64);
        q0 += __shfl_down(q0, off, 64);
        q1 += __shfl_down(q1, off, 64);
    }
    __shared__ float red[4][4];
    int wave = tid >> 6, lane = tid & 63;
    if (lane == 0) {
        red[wave][0] = s0; red[wave][1] = s1;
        red[wave][2] = q0; red[wave][3] = q1;
    }
    __syncthreads();
    if (tid == 0) {
        float t0 = 0.f, t1 = 0.f, t2 = 0.f, t3 = 0.f;
#pragma unroll
        for (int wv = 0; wv < 4; ++wv) {
            t0 += red[wv][0]; t1 += red[wv][1];
            t2 += red[wv][2]; t3 += red[wv][3];
        }
        int ch0 = 2 * (n & 15);
        atomicAdd(stats + ch0,          t0);
        atomicAdd(stats + ch0 + 1,      t1);
        atomicAdd(stats + 32 + ch0,     t2);
        atomicAdd(stats + 32 + ch0 + 1, t3);
    }
}

// ---------------------------------------------------------------------------
// K4: fold BN + 1/128 scale into per-channel affine.
// ---------------------------------------------------------------------------
__global__ void finalize_kernel(const float* __restrict__ stats,
                                const float* __restrict__ gamma,
                                const float* __restrict__ beta,
                                float* __restrict__ AB) {
    int ch = threadIdx.x;
    if (ch < 2 * IC) {
        const float invN = 1.f / (float)BN_N;
        float mean = stats[ch] * invN;
        float var  = stats[32 + ch] * invN - mean * mean;
        float rs   = rsqrtf(var + BN_EPS);
        float a    = gamma[ch] * rs;
        AB[ch]      = a * (1.f / 128.f);
        AB[32 + ch] = (beta[ch] - a * mean) * (1.f / 128.f);
    }
}

// ---------------------------------------------------------------------------
// masked tap setup (unpadded planes; FIRST-step deform reads only)
// ---------------------------------------------------------------------------
__device__ __forceinline__ void tap_setup(float py, float px,
                                          int* o, float* wt) {
    float ffy = floorf(py), ffx = floorf(px);
    int y0 = (int)ffy, x0 = (int)ffx;
    float wy1 = py - ffy, wy0 = 1.f - wy1;
    float wx1 = px - ffx, wx0 = 1.f - wx1;
    bool vy0 = (unsigned)y0 < (unsigned)H, vy1 = (unsigned)(y0 + 1) < (unsigned)H;
    bool vx0 = (unsigned)x0 < (unsigned)W, vx1 = (unsigned)(x0 + 1) < (unsigned)W;
    int yc0 = min(max(y0, 0), H - 1), yc1 = min(max(y0 + 1, 0), H - 1);
    int xc0 = min(max(x0, 0), W - 1), xc1 = min(max(x0 + 1, 0), W - 1);
    o[0] = yc0 * W + xc0; o[1] = yc0 * W + xc1;
    o[2] = yc1 * W + xc0; o[3] = yc1 * W + xc1;
    wt[0] = (vy0 && vx0) ? wy0 * wx0 : 0.f;
    wt[1] = (vy0 && vx1) ? wy0 * wx1 : 0.f;
    wt[2] = (vy1 && vx0) ? wy1 * wx0 : 0.f;
    wt[3] = (vy1 && vx1) ? wy1 * wx1 : 0.f;
}

// ---------------------------------------------------------------------------
// fast tap setup for guard-padded planes
// ---------------------------------------------------------------------------
__device__ __forceinline__ void tap_fast(float py, float px,
                                         int& o, float* wt) {
    float pyc = fminf(fmaxf(py, -1.f), 256.f);
    float pxc = fminf(fmaxf(px, -1.f), 256.f);
    float fy = floorf(pyc), fx = floorf(pxc);
    int y0 = (int)fy, x0 = (int)fx;
    float wy1 = pyc - fy, wy0 = 1.f - wy1;
    float wx1 = pxc - fx, wx0 = 1.f - wx1;
    o = (y0 + 1) * PW + (x0 + 1);
    wt[0] = wy0 * wx0; wt[1] = wy0 * wx1;
    wt[2] = wy1 * wx0; wt[3] = wy1 * wx1;
}

// ---------------------------------------------------------------------------
// K5: one squaring step + fused f-warp + incremental fuse matvec.
// ---------------------------------------------------------------------------
template <bool FIRST, bool LAST>
__global__ __launch_bounds__(256) void step_kernel(
    const __half2* __restrict__ vinRaw, const __half2* __restrict__ vinPad,
    __half2* __restrict__ voutPad, const __half* __restrict__ f16p,
    const float* __restrict__ AB, const float* __restrict__ fw,
    const float* __restrict__ fb, __half* __restrict__ accp,
    float* __restrict__ out, int step) {
    int blk = blockIdx.x;             // 2048
    int xcd = blk & 7;
    int i   = blk >> 3;
    int b   = i >> 5;
    int h   = (xcd << 5) | (i & 31);
    int tx  = threadIdx.x;
    int idx_raw = h * W + tx;
    int idx_pad = (h + 1) * PW + tx + 1;
    const size_t baseR = (size_t)b * IC * PLANE;
    const size_t baseP = (size_t)b * IC * PSZ;

    float mv[IC];

#pragma unroll 2
    for (int g = 0; g < 4; ++g) {
        float a0j[4], b0j[4], a1j[4], b1j[4];
        float fy[4], fx[4];
        float wt[4][4];
        int   ob[4];
        int   om[4][4];
        const __half2* pl[4];
        float2 vc[4];

#pragma unroll
        for (int j = 0; j < 4; ++j) {
            int c = 4 * g + j;
            if (FIRST) {
                pl[j] = vinRaw + baseR + (size_t)c * PLANE;
                vc[j] = __half22float2(pl[j][idx_raw]);
            } else {
                pl[j] = vinPad + baseP + (size_t)c * PSZ;
                vc[j] = __half22float2(pl[j][idx_pad]);
            }
        }

#pragma unroll
        for (int j = 0; j < 4; ++j) {
            int c = 4 * g + j;
            if (FIRST) {
                a0j[j] = AB[2 * c];     b0j[j] = AB[32 + 2 * c];
                a1j[j] = AB[2 * c + 1]; b1j[j] = AB[32 + 2 * c + 1];
                fy[j] = fmaf(a0j[j], vc[j].x, b0j[j]);
                fx[j] = fmaf(a1j[j], vc[j].y, b1j[j]);
                tap_setup((float)h + fy[j], (float)tx + fx[j], om[j], wt[j]);
            } else {
                fy[j] = vc[j].x;
                fx[j] = vc[j].y;
                tap_fast((float)h + fy[j], (float)tx + fx[j], ob[j], wt[j]);
            }
        }

        float2 t[4][4];
#pragma unroll
        for (int j = 0; j < 4; ++j) {
            if (FIRST) {
#pragma unroll
                for (int k = 0; k < 4; ++k)
                    t[j][k] = __half22float2(pl[j][om[j][k]]);
            } else {
                t[j][0] = __half22float2(pl[j][ob[j]]);
                t[j][1] = __half22float2(pl[j][ob[j] + 1]);
                t[j][2] = __half22float2(pl[j][ob[j] + PW]);
                t[j][3] = __half22float2(pl[j][ob[j] + PW + 1]);
            }
        }

        float ny[4], nx[4];
        int   pb_[4];
        float pw_[4][4];
#pragma unroll
        for (int j = 0; j < 4; ++j) {
            int c = 4 * g + j;
            float Sy = wt[j][0] * t[j][0].x + wt[j][1] * t[j][1].x
                     + wt[j][2] * t[j][2].x + wt[j][3] * t[j][3].x;
            float Sx = wt[j][0] * t[j][0].y + wt[j][1] * t[j][1].y
                     + wt[j][2] * t[j][2].y + wt[j][3] * t[j][3].y;
            if (FIRST) {
                float Ws = wt[j][0] + wt[j][1] + wt[j][2] + wt[j][3];
                ny[j] = fy[j] + fmaf(a0j[j], Sy, b0j[j] * Ws);
                nx[j] = fx[j] + fmaf(a1j[j], Sx, b1j[j] * Ws);
            } else {
                ny[j] = fy[j] + Sy;
                nx[j] = fx[j] + Sx;
            }
            if (!LAST)
                voutPad[baseP + (size_t)c * PSZ + idx_pad] =
                    __float22half2_rn(make_float2(ny[j], nx[j]));
            tap_fast((float)h + ny[j], (float)tx + nx[j], pb_[j], pw_[j]);
        }

#pragma unroll
        for (int j = 0; j < 4; ++j) {
            int c = 4 * g + j;
            const __half* fp = f16p + baseP + (size_t)c * PSZ;
            mv[c] = pw_[j][0] * __half2float(fp[pb_[j]])
                  + pw_[j][1] * __half2float(fp[pb_[j] + 1])
                  + pw_[j][2] * __half2float(fp[pb_[j] + PW])
                  + pw_[j][3] * __half2float(fp[pb_[j] + PW + 1]);
        }
    }

    // incremental fuse: acc_o (+)= fw[o,:,step] . mv  (interleaved accp)
    __half* ap = accp + ((size_t)b * PLANE + idx_raw) * IC;
    float prev[IC];
    if (!FIRST) {
        float4 p0 = ((const float4*)ap)[0];
        float4 p1 = ((const float4*)ap)[1];
        const __half2* ph = (const __half2*)&p0;
#pragma unroll
        for (int k = 0; k < 4; ++k) {
            float2 v = __half22float2(ph[k]);
            prev[2 * k] = v.x; prev[2 * k + 1] = v.y;
        }
        const __half2* qh = (const __half2*)&p1;
#pragma unroll
        for (int k = 0; k < 4; ++k) {
            float2 v = __half22float2(qh[k]);
            prev[8 + 2 * k] = v.x; prev[8 + 2 * k + 1] = v.y;
        }
    }

    float a[IC];
#pragma unroll
    for (int o2 = 0; o2 < IC; ++o2) {
        a[o2] = FIRST ? fb[o2] : prev[o2];
#pragma unroll
        for (int c = 0; c < IC; ++c)
            a[o2] = fmaf(fw[(o2 * IC + c) * NSTEPS + step], mv[c], a[o2]);
    }

    if (LAST) {
#pragma unroll
        for (int o2 = 0; o2 < IC; ++o2)
            out[baseR + (size_t)o2 * PLANE + idx_raw] = a[o2];
    } else {
        float4 s0, s1;
        __half2* sh = (__half2*)&s0;
#pragma unroll
        for (int k = 0; k < 4; ++k)
            sh[k] = __float22half2_rn(make_float2(a[2 * k], a[2 * k + 1]));
        __half2* th = (__half2*)&s1;
#pragma unroll
        for (int k = 0; k < 4; ++k)
            th[k] = __float22half2_rn(make_float2(a[8 + 2 * k], a[9 + 2 * k]));
        ((float4*)ap)[0] = s0;
        ((float4*)ap)[1] = s1;
    }
}

// ---------------------------------------------------------------------------
extern "C" void kernel_launch(void* const* d_in, const int* in_sizes, int n_in,
                              void* d_out, int out_size, void* d_ws,
                              size_t ws_size, hipStream_t stream) {
    const float* f      = (const float*)d_in[0];
    const float* vec_w  = (const float*)d_in[1];
    const float* vec_b  = (const float*)d_in[2];
    const float* gamma  = (const float*)d_in[3];
    const float* beta   = (const float*)d_in[4];
    const float* fuse_w = (const float*)d_in[5];
    const float* fuse_b = (const float*)d_in[6];
    float* out = (float*)d_out;

    char* ws = (char*)d_ws;
    const size_t rawB  = (size_t)NFIELDS * PLANE * sizeof(__half2);
    const size_t padB2 = (size_t)NFIELDS * PSZ * sizeof(__half2);
    const size_t padB1 = (size_t)NFIELDS * PSZ * sizeof(__half);
    const size_t accB  = (size_t)NFIELDS * PLANE * sizeof(__half);
    __half2* bufRaw = (__half2*)ws;
    __half2* bufA   = (__half2*)(ws + rawB);
    __half2* bufB   = (__half2*)(ws + rawB + padB2);
    __half*  f16p   = (__half*)(ws + rawB + 2 * padB2);
    __half*  accp   = (__half*)(ws + rawB + 2 * padB2 + padB1);
    __half2* wTh    = (__half2*)(ws + rawB + 2 * padB2 + padB1 + accB);
    float*   stats  = (float*)(wTh + IC * 9 * 16);
    float*   AB     = stats + 64;

    hipMemsetAsync(stats, 0, 64 * sizeof(float), stream);
    transpose_w_kernel<<<1, 512, 0, stream>>>(vec_w, wTh);
    guard_zero_kernel<<<NFIELDS, 256, 0, stream>>>(
        (unsigned*)bufA, (unsigned*)bufB, (unsigned short*)f16p);
    conv_kernel<<<1024, 256, 0, stream>>>(f, wTh, vec_b, bufRaw, f16p);
    stats_kernel<<<NFIELDS * 16, 256, 0, stream>>>(bufRaw, stats);
    finalize_kernel<<<1, 64, 0, stream>>>(stats, gamma, beta, AB);

    // s=0: bufRaw -> bufA; s odd: bufA -> bufB; s even>0: bufB -> bufA
    for (int s = 0; s < NSTEPS; ++s) {
        const __half2* vinPad = (s & 1) ? bufA : bufB;
        __half2*       voutP  = (s & 1) ? bufB : bufA;
        if (s == 0)
            step_kernel<true, false><<<2048, 256, 0, stream>>>(
                bufRaw, (const __half2*)nullptr, bufA, f16p, AB,
                fuse_w, fuse_b, accp, out, s);
        else if (s < NSTEPS - 1)
            step_kernel<false, false><<<2048, 256, 0, stream>>>(
                (const __half2*)nullptr, vinPad, voutP, f16p, AB,
                fuse_w, fuse_b, accp, out, s);
        else
            step_kernel<false, true><<<2048, 256, 0, stream>>>(
                (const __half2*)nullptr, vinPad, (__half2*)nullptr, f16p, AB,
                fuse_w, fuse_b, accp, out, s);
    }
}

// Round 3
// 495.153 us; speedup vs baseline: 1.0198x; 1.0198x over previous
//
#include <hip/hip_runtime.h>
#include <hip/hip_fp16.h>

#define H 256
#define W 256
#define BS 8
#define IC 16          // in_ch (flow fields per batch; also out channels)
#define OCH 32         // conv output channels = 2*IC
#define NSTEPS 7
#define PLANE (H*W)            // 65536
#define NFIELDS (BS*IC)        // 128
#define BN_N (BS*PLANE)        // 524288
#define BN_EPS 1e-5f
// padded plane: interior (y,x) at (y+1, x+1), pitch 260, rows 0..258 used
#define PW 260
#define PSZ (260 * 260)

// ---------------------------------------------------------------------------
// K0: vec_w [oc][ic][3][3] -> wTh [(ic*9+k)][p] as half2 pairs (oc 2p, 2p+1)
// ---------------------------------------------------------------------------
__global__ void transpose_w_kernel(const float* __restrict__ w,
                                   __half2* __restrict__ wTh) {
    for (int idx = threadIdx.x; idx < IC * 9 * 16; idx += blockDim.x) {
        int rc = idx >> 4;        // ic*9+k
        int p  = idx & 15;
        float lo = w[(2 * p) * (IC * 9) + rc];
        float hi = w[(2 * p + 1) * (IC * 9) + rc];
        wTh[idx] = __floats2half2_rn(lo, hi);
    }
}

// ---------------------------------------------------------------------------
// K1: zero the guard borders of the two padded step buffers + padded f16.
// ---------------------------------------------------------------------------
__global__ void guard_zero_kernel(unsigned* __restrict__ bufA,
                                  unsigned* __restrict__ bufB,
                                  unsigned short* __restrict__ f16p) {
    int p = blockIdx.x;           // 128 planes
    size_t pb = (size_t)p * PSZ;
    for (int i = threadIdx.x; i < 2064; i += blockDim.x) {
        int row, col;
        if (i < 1040) {
            int r = i / 260;
            row = (r == 0) ? 0 : 256 + r;     // 0,257,258,259
            col = i - r * 260;
        } else {
            int j = i - 1040;
            int c = j / 256;
            col = (c == 0) ? 0 : 256 + c;     // 0,257,258,259
            row = 1 + (j - c * 256);
        }
        size_t off = pb + (size_t)row * PW + col;
        bufA[off] = 0u;
        bufB[off] = 0u;
        f16p[off] = 0;
    }
}

// ---------------------------------------------------------------------------
// K2: 3x3 conv (16->32) + bias in PACKED FP16.
// R3 rewrite: weights via wave-uniform global loads (scalar s_load path,
// proven R1); single staging phase (all 16 ic, one barrier); float4
// vectorized staging with no integer division; f16p written directly from
// staging registers (own-tile interior, no LDS re-read).
// ---------------------------------------------------------------------------
__global__ __launch_bounds__(256, 4) void conv_kernel(
    const float* __restrict__ f, const __half2* __restrict__ wTh,
    const float* __restrict__ vec_b, __half2* __restrict__ vec_out,
    __half* __restrict__ f16p) {
    // col origin = tx0-4; compute reads cols [3,36]; rows [0,17] = ty0-1..ty0+16
    __shared__ __align__(16) __half sf[16][18][40];   // 23 KB

    int blk = blockIdx.x;              // 1024
    int xcd = blk & 7;
    int i   = blk >> 3;
    int b   = i >> 4;
    int j   = i & 15;
    int ty0 = ((xcd << 1) | (j >> 3)) * 16;
    int tx0 = (j & 7) * 32;
    int tid = threadIdx.x;
    int tyl = tid >> 5, txl = tid & 31;
    int y0p = ty0 + tyl, y1p = ty0 + tyl + 8, x = tx0 + txl;

    // ---- staging: tid -> (sic = tid>>4, st = tid&15); st<10 loads a float4
    // per row covering gx in [tx0-4, tx0+36). st in [1,8] also writes the
    // own-tile interior f16p copy (rows r=1..16 are always in-plane there).
    {
        int sic = tid >> 4;
        int st  = tid & 15;
        if (st < 10) {
            int gx0 = tx0 - 4 + 4 * st;
            const float* fpl = f + (size_t)(b * IC + sic) * PLANE;
            size_t fb16 = (size_t)(b * IC + sic) * PSZ;
            bool full = (gx0 >= 0) && (gx0 + 3 < W);
            bool own  = (st >= 1) && (st <= 8);
#pragma unroll
            for (int r = 0; r < 18; ++r) {
                int gy = ty0 - 1 + r;
                float4 v = make_float4(0.f, 0.f, 0.f, 0.f);
                if ((unsigned)gy < (unsigned)H) {
                    if (full) {
                        v = *(const float4*)(fpl + (size_t)gy * W + gx0);
                    } else {
                        if ((unsigned)(gx0 + 0) < (unsigned)W) v.x = fpl[(size_t)gy * W + gx0 + 0];
                        if ((unsigned)(gx0 + 1) < (unsigned)W) v.y = fpl[(size_t)gy * W + gx0 + 1];
                        if ((unsigned)(gx0 + 2) < (unsigned)W) v.z = fpl[(size_t)gy * W + gx0 + 2];
                        if ((unsigned)(gx0 + 3) < (unsigned)W) v.w = fpl[(size_t)gy * W + gx0 + 3];
                    }
                }
                __half2 h01 = __floats2half2_rn(v.x, v.y);
                __half2 h23 = __floats2half2_rn(v.z, v.w);
                union { __half2 h[2]; float2 f2; } u;
                u.h[0] = h01; u.h[1] = h23;
                *(float2*)&sf[sic][r][4 * st] = u.f2;   // 8B-aligned LDS write
                if (own && r >= 1 && r <= 16) {
                    // gy,gx fully in-plane here
                    __half* fp = f16p + fb16 + (size_t)(gy + 1) * PW + (gx0 + 1);
                    fp[0] = __low2half(h01);
                    fp[1] = __high2half(h01);
                    fp[2] = __low2half(h23);
                    fp[3] = __high2half(h23);
                }
            }
        }
    }

    __half2 acc0[16], acc1[16];
#pragma unroll
    for (int p = 0; p < 16; ++p) {
        __half2 bp = __floats2half2_rn(vec_b[2 * p], vec_b[2 * p + 1]);
        acc0[p] = bp; acc1[p] = bp;
    }

    __syncthreads();

#pragma unroll 2
    for (int ic = 0; ic < 16; ++ic) {
#pragma unroll
        for (int k = 0; k < 9; ++k) {
            int ky = k / 3, kx = k - ky * 3;
            __half2 fv0 = __half2half2(sf[ic][tyl + ky][txl + kx + 3]);
            __half2 fv1 = __half2half2(sf[ic][tyl + 8 + ky][txl + kx + 3]);
            const __half2* wrow = wTh + (ic * 9 + k) * 16;   // wave-uniform -> s_load
#pragma unroll
            for (int p = 0; p < 16; ++p) {
                __half2 wv = wrow[p];
                acc0[p] = __hfma2(fv0, wv, acc0[p]);
                acc1[p] = __hfma2(fv1, wv, acc1[p]);
            }
        }
    }

#pragma unroll
    for (int c = 0; c < IC; ++c) {
        size_t pb = (size_t)(b * IC + c) * PLANE;
        vec_out[pb + y0p * W + x] = acc0[c];
        vec_out[pb + y1p * W + x] = acc1[c];
    }
}

// ---------------------------------------------------------------------------
// K3: per-channel sum / sumsq over the half2 conv output (unpadded).
// float4 (4x half2) vectorized reads.
// ---------------------------------------------------------------------------
__global__ __launch_bounds__(256) void stats_kernel(
    const __half2* __restrict__ vec, float* __restrict__ stats) {
    int blk   = blockIdx.x;            // 2048
    int n     = blk >> 4;
    int chunk = blk & 15;
    const float4* p4 = (const float4*)(vec + (size_t)n * PLANE + chunk * 4096);
    int tid = threadIdx.x;

    float s0 = 0.f, s1 = 0.f, q0 = 0.f, q1 = 0.f;
#pragma unroll 2
    for (int i = tid; i < 1024; i += 256) {
        float4 w = p4[i];
        const __half2* hh = (const __half2*)&w;
#pragma unroll
        for (int q = 0; q < 4; ++q) {
            float2 v = __half22float2(hh[q]);
            s0 += v.x; s1 += v.y;
            q0 = fmaf(v.x, v.x, q0);
            q1 = fmaf(v.y, v.y, q1);
        }
    }
#pragma unroll
    for (int off = 32; off > 0; off >>= 1) {
        s0 += __shfl_down(s0, off, 64);
        s1 += __shfl_down(s1, off, 64);
        q0 += __shfl_down(q0, off, 64);
        q1 += __shfl_down(q1, off, 64);
    }
    __shared__ float red[4][4];
    int wave = tid >> 6, lane = tid & 63;
    if (lane == 0) {
        red[wave][0] = s0; red[wave][1] = s1;
        red[wave][2] = q0; red[wave][3] = q1;
    }
    __syncthreads();
    if (tid == 0) {
        float t0 = 0.f, t1 = 0.f, t2 = 0.f, t3 = 0.f;
#pragma unroll
        for (int wv = 0; wv < 4; ++wv) {
            t0 += red[wv][0]; t1 += red[wv][1];
            t2 += red[wv][2]; t3 += red[wv][3];
        }
        int ch0 = 2 * (n & 15);
        atomicAdd(stats + ch0,          t0);
        atomicAdd(stats + ch0 + 1,      t1);
        atomicAdd(stats + 32 + ch0,     t2);
        atomicAdd(stats + 32 + ch0 + 1, t3);
    }
}

// ---------------------------------------------------------------------------
// K4: fold BN + 1/128 scale into per-channel affine.
// ---------------------------------------------------------------------------
__global__ void finalize_kernel(const float* __restrict__ stats,
                                const float* __restrict__ gamma,
                                const float* __restrict__ beta,
                                float* __restrict__ AB) {
    int ch = threadIdx.x;
    if (ch < 2 * IC) {
        const float invN = 1.f / (float)BN_N;
        float mean = stats[ch] * invN;
        float var  = stats[32 + ch] * invN - mean * mean;
        float rs   = rsqrtf(var + BN_EPS);
        float a    = gamma[ch] * rs;
        AB[ch]      = a * (1.f / 128.f);
        AB[32 + ch] = (beta[ch] - a * mean) * (1.f / 128.f);
    }
}

// ---------------------------------------------------------------------------
// masked tap setup (unpadded planes; FIRST-step deform reads only)
// ---------------------------------------------------------------------------
__device__ __forceinline__ void tap_setup(float py, float px,
                                          int* o, float* wt) {
    float ffy = floorf(py), ffx = floorf(px);
    int y0 = (int)ffy, x0 = (int)ffx;
    float wy1 = py - ffy, wy0 = 1.f - wy1;
    float wx1 = px - ffx, wx0 = 1.f - wx1;
    bool vy0 = (unsigned)y0 < (unsigned)H, vy1 = (unsigned)(y0 + 1) < (unsigned)H;
    bool vx0 = (unsigned)x0 < (unsigned)W, vx1 = (unsigned)(x0 + 1) < (unsigned)W;
    int yc0 = min(max(y0, 0), H - 1), yc1 = min(max(y0 + 1, 0), H - 1);
    int xc0 = min(max(x0, 0), W - 1), xc1 = min(max(x0 + 1, 0), W - 1);
    o[0] = yc0 * W + xc0; o[1] = yc0 * W + xc1;
    o[2] = yc1 * W + xc0; o[3] = yc1 * W + xc1;
    wt[0] = (vy0 && vx0) ? wy0 * wx0 : 0.f;
    wt[1] = (vy0 && vx1) ? wy0 * wx1 : 0.f;
    wt[2] = (vy1 && vx0) ? wy1 * wx0 : 0.f;
    wt[3] = (vy1 && vx1) ? wy1 * wx1 : 0.f;
}

// ---------------------------------------------------------------------------
// fast tap setup for guard-padded planes
// ---------------------------------------------------------------------------
__device__ __forceinline__ void tap_fast(float py, float px,
                                         int& o, float* wt) {
    float pyc = fminf(fmaxf(py, -1.f), 256.f);
    float pxc = fminf(fmaxf(px, -1.f), 256.f);
    float fy = floorf(pyc), fx = floorf(pxc);
    int y0 = (int)fy, x0 = (int)fx;
    float wy1 = pyc - fy, wy0 = 1.f - wy1;
    float wx1 = pxc - fx, wx0 = 1.f - wx1;
    o = (y0 + 1) * PW + (x0 + 1);
    wt[0] = wy0 * wx0; wt[1] = wy0 * wx1;
    wt[2] = wy1 * wx0; wt[3] = wy1 * wx1;
}

// ---------------------------------------------------------------------------
// K5: one squaring step + fused f-warp + incremental fuse matvec.
// ---------------------------------------------------------------------------
template <bool FIRST, bool LAST>
__global__ __launch_bounds__(256) void step_kernel(
    const __half2* __restrict__ vinRaw, const __half2* __restrict__ vinPad,
    __half2* __restrict__ voutPad, const __half* __restrict__ f16p,
    const float* __restrict__ AB, const float* __restrict__ fw,
    const float* __restrict__ fb, __half* __restrict__ accp,
    float* __restrict__ out, int step) {
    int blk = blockIdx.x;             // 2048
    int xcd = blk & 7;
    int i   = blk >> 3;
    int b   = i >> 5;
    int h   = (xcd << 5) | (i & 31);
    int tx  = threadIdx.x;
    int idx_raw = h * W + tx;
    int idx_pad = (h + 1) * PW + tx + 1;
    const size_t baseR = (size_t)b * IC * PLANE;
    const size_t baseP = (size_t)b * IC * PSZ;

    float mv[IC];

#pragma unroll 2
    for (int g = 0; g < 4; ++g) {
        float a0j[4], b0j[4], a1j[4], b1j[4];
        float fy[4], fx[4];
        float wt[4][4];
        int   ob[4];
        int   om[4][4];
        const __half2* pl[4];
        float2 vc[4];

#pragma unroll
        for (int j = 0; j < 4; ++j) {
            int c = 4 * g + j;
            if (FIRST) {
                pl[j] = vinRaw + baseR + (size_t)c * PLANE;
                vc[j] = __half22float2(pl[j][idx_raw]);
            } else {
                pl[j] = vinPad + baseP + (size_t)c * PSZ;
                vc[j] = __half22float2(pl[j][idx_pad]);
            }
        }

#pragma unroll
        for (int j = 0; j < 4; ++j) {
            int c = 4 * g + j;
            if (FIRST) {
                a0j[j] = AB[2 * c];     b0j[j] = AB[32 + 2 * c];
                a1j[j] = AB[2 * c + 1]; b1j[j] = AB[32 + 2 * c + 1];
                fy[j] = fmaf(a0j[j], vc[j].x, b0j[j]);
                fx[j] = fmaf(a1j[j], vc[j].y, b1j[j]);
                tap_setup((float)h + fy[j], (float)tx + fx[j], om[j], wt[j]);
            } else {
                fy[j] = vc[j].x;
                fx[j] = vc[j].y;
                tap_fast((float)h + fy[j], (float)tx + fx[j], ob[j], wt[j]);
            }
        }

        float2 t[4][4];
#pragma unroll
        for (int j = 0; j < 4; ++j) {
            if (FIRST) {
#pragma unroll
                for (int k = 0; k < 4; ++k)
                    t[j][k] = __half22float2(pl[j][om[j][k]]);
            } else {
                t[j][0] = __half22float2(pl[j][ob[j]]);
                t[j][1] = __half22float2(pl[j][ob[j] + 1]);
                t[j][2] = __half22float2(pl[j][ob[j] + PW]);
                t[j][3] = __half22float2(pl[j][ob[j] + PW + 1]);
            }
        }

        float ny[4], nx[4];
        int   pb_[4];
        float pw_[4][4];
#pragma unroll
        for (int j = 0; j < 4; ++j) {
            int c = 4 * g + j;
            float Sy = wt[j][0] * t[j][0].x + wt[j][1] * t[j][1].x
                     + wt[j][2] * t[j][2].x + wt[j][3] * t[j][3].x;
            float Sx = wt[j][0] * t[j][0].y + wt[j][1] * t[j][1].y
                     + wt[j][2] * t[j][2].y + wt[j][3] * t[j][3].y;
            if (FIRST) {
                float Ws = wt[j][0] + wt[j][1] + wt[j][2] + wt[j][3];
                ny[j] = fy[j] + fmaf(a0j[j], Sy, b0j[j] * Ws);
                nx[j] = fx[j] + fmaf(a1j[j], Sx, b1j[j] * Ws);
            } else {
                ny[j] = fy[j] + Sy;
                nx[j] = fx[j] + Sx;
            }
            if (!LAST)
                voutPad[baseP + (size_t)c * PSZ + idx_pad] =
                    __float22half2_rn(make_float2(ny[j], nx[j]));
            tap_fast((float)h + ny[j], (float)tx + nx[j], pb_[j], pw_[j]);
        }

#pragma unroll
        for (int j = 0; j < 4; ++j) {
            int c = 4 * g + j;
            const __half* fp = f16p + baseP + (size_t)c * PSZ;
            mv[c] = pw_[j][0] * __half2float(fp[pb_[j]])
                  + pw_[j][1] * __half2float(fp[pb_[j] + 1])
                  + pw_[j][2] * __half2float(fp[pb_[j] + PW])
                  + pw_[j][3] * __half2float(fp[pb_[j] + PW + 1]);
        }
    }

    // incremental fuse: acc_o (+)= fw[o,:,step] . mv  (interleaved accp)
    __half* ap = accp + ((size_t)b * PLANE + idx_raw) * IC;
    float prev[IC];
    if (!FIRST) {
        float4 p0 = ((const float4*)ap)[0];
        float4 p1 = ((const float4*)ap)[1];
        const __half2* ph = (const __half2*)&p0;
#pragma unroll
        for (int k = 0; k < 4; ++k) {
            float2 v = __half22float2(ph[k]);
            prev[2 * k] = v.x; prev[2 * k + 1] = v.y;
        }
        const __half2* qh = (const __half2*)&p1;
#pragma unroll
        for (int k = 0; k < 4; ++k) {
            float2 v = __half22float2(qh[k]);
            prev[8 + 2 * k] = v.x; prev[8 + 2 * k + 1] = v.y;
        }
    }

    float a[IC];
#pragma unroll
    for (int o2 = 0; o2 < IC; ++o2) {
        a[o2] = FIRST ? fb[o2] : prev[o2];
#pragma unroll
        for (int c = 0; c < IC; ++c)
            a[o2] = fmaf(fw[(o2 * IC + c) * NSTEPS + step], mv[c], a[o2]);
    }

    if (LAST) {
#pragma unroll
        for (int o2 = 0; o2 < IC; ++o2)
            out[baseR + (size_t)o2 * PLANE + idx_raw] = a[o2];
    } else {
        float4 s0, s1;
        __half2* sh = (__half2*)&s0;
#pragma unroll
        for (int k = 0; k < 4; ++k)
            sh[k] = __float22half2_rn(make_float2(a[2 * k], a[2 * k + 1]));
        __half2* th = (__half2*)&s1;
#pragma unroll
        for (int k = 0; k < 4; ++k)
            th[k] = __float22half2_rn(make_float2(a[8 + 2 * k], a[9 + 2 * k]));
        ((float4*)ap)[0] = s0;
        ((float4*)ap)[1] = s1;
    }
}

// ---------------------------------------------------------------------------
extern "C" void kernel_launch(void* const* d_in, const int* in_sizes, int n_in,
                              void* d_out, int out_size, void* d_ws,
                              size_t ws_size, hipStream_t stream) {
    const float* f      = (const float*)d_in[0];
    const float* vec_w  = (const float*)d_in[1];
    const float* vec_b  = (const float*)d_in[2];
    const float* gamma  = (const float*)d_in[3];
    const float* beta   = (const float*)d_in[4];
    const float* fuse_w = (const float*)d_in[5];
    const float* fuse_b = (const float*)d_in[6];
    float* out = (float*)d_out;

    char* ws = (char*)d_ws;
    const size_t rawB  = (size_t)NFIELDS * PLANE * sizeof(__half2);
    const size_t padB2 = (size_t)NFIELDS * PSZ * sizeof(__half2);
    const size_t padB1 = (size_t)NFIELDS * PSZ * sizeof(__half);
    const size_t accB  = (size_t)NFIELDS * PLANE * sizeof(__half);
    __half2* bufRaw = (__half2*)ws;
    __half2* bufA   = (__half2*)(ws + rawB);
    __half2* bufB   = (__half2*)(ws + rawB + padB2);
    __half*  f16p   = (__half*)(ws + rawB + 2 * padB2);
    __half*  accp   = (__half*)(ws + rawB + 2 * padB2 + padB1);
    __half2* wTh    = (__half2*)(ws + rawB + 2 * padB2 + padB1 + accB);
    float*   stats  = (float*)(wTh + IC * 9 * 16);
    float*   AB     = stats + 64;

    hipMemsetAsync(stats, 0, 64 * sizeof(float), stream);
    transpose_w_kernel<<<1, 512, 0, stream>>>(vec_w, wTh);
    guard_zero_kernel<<<NFIELDS, 256, 0, stream>>>(
        (unsigned*)bufA, (unsigned*)bufB, (unsigned short*)f16p);
    conv_kernel<<<1024, 256, 0, stream>>>(f, wTh, vec_b, bufRaw, f16p);
    stats_kernel<<<NFIELDS * 16, 256, 0, stream>>>(bufRaw, stats);
    finalize_kernel<<<1, 64, 0, stream>>>(stats, gamma, beta, AB);

    // s=0: bufRaw -> bufA; s odd: bufA -> bufB; s even>0: bufB -> bufA
    for (int s = 0; s < NSTEPS; ++s) {
        const __half2* vinPad = (s & 1) ? bufA : bufB;
        __half2*       voutP  = (s & 1) ? bufB : bufA;
        if (s == 0)
            step_kernel<true, false><<<2048, 256, 0, stream>>>(
                bufRaw, (const __half2*)nullptr, bufA, f16p, AB,
                fuse_w, fuse_b, accp, out, s);
        else if (s < NSTEPS - 1)
            step_kernel<false, false><<<2048, 256, 0, stream>>>(
                (const __half2*)nullptr, vinPad, voutP, f16p, AB,
                fuse_w, fuse_b, accp, out, s);
        else
            step_kernel<false, true><<<2048, 256, 0, stream>>>(
                (const __half2*)nullptr, vinPad, (__half2*)nullptr, f16p, AB,
                fuse_w, fuse_b, accp, out, s);
    }
}